// Round 1
// baseline (1501.599 us; speedup 1.0000x reference)
//
#include <hip/hip_runtime.h>

// ---------------------------------------------------------------------------
// ConditionalVariationalModule: B=1024, S=256, INPUT=256, LATENT=128, HIDDEN=256
// Decomposition:
//   K1: Cq[b,s,:] = h@ (qW1[0:256]+qW1[384:640]) + qb1   (parallel GEMM, frag-packed out)
//   K2: sequential posterior scan over s (64 WGs x 16 batch rows, weights in VGPRs)
//   K3: prior MLP over all (b,s) with z_prev (parallel, overwrites Cq region)
// Outputs (fp32): z | pm | plv | qm | qlv, each [B,S,128]. Cq lives in pm|plv.
// ---------------------------------------------------------------------------

typedef __attribute__((ext_vector_type(8))) short bfrag8;   // 8 bf16 = 4 VGPR
typedef __attribute__((ext_vector_type(4))) float facc4;    // MFMA accum

__device__ __forceinline__ unsigned short f2bf(float x) {
  unsigned int u = __float_as_uint(x);
  u = (u + 0x7fffu + ((u >> 16) & 1u)) >> 16;   // round-to-nearest-even
  return (unsigned short)u;
}
__device__ __forceinline__ unsigned int pk2(float a, float b) {
  return (unsigned int)f2bf(a) | ((unsigned int)f2bf(b) << 16);
}
__device__ __forceinline__ facc4 mfma_bf16(bfrag8 a, bfrag8 b, facc4 c) {
  return __builtin_amdgcn_mfma_f32_16x16x32_bf16(a, b, c, 0, 0, 0);
}

// ---------------------------------------------------------------------------
// Pack a [K,256] fp32 weight (optionally sum of two) into B-fragment order:
// dst[((nt*KT + kt)*64 + lane)*8 + i] = bf16( W[kt*32 + (lane>>4)*8 + i][nt*16 + (lane&15)] )
// ---------------------------------------------------------------------------
__global__ void pack_weights(const float* __restrict__ src, const float* __restrict__ src2,
                             unsigned short* __restrict__ dst, int KT) {
  int t = blockIdx.x * 256 + threadIdx.x;
  if (t >= 16 * KT * 64) return;
  int l  = t & 63;
  int kt = (t >> 6) % KT;
  int nt = t / (64 * KT);
  int n  = nt * 16 + (l & 15);
  int k0 = kt * 32 + (l >> 4) * 8;
  unsigned int o[4];
#pragma unroll
  for (int p = 0; p < 4; ++p) {
    float a = src[(size_t)(k0 + 2 * p) * 256 + n];
    float b = src[(size_t)(k0 + 2 * p + 1) * 256 + n];
    if (src2) {
      a += src2[(size_t)(k0 + 2 * p) * 256 + n];
      b += src2[(size_t)(k0 + 2 * p + 1) * 256 + n];
    }
    o[p] = pk2(a, b);
  }
  *(uint4*)(dst + (size_t)t * 8) = make_uint4(o[0], o[1], o[2], o[3]);
}

// ---------------------------------------------------------------------------
// K1: Cq (frag-packed fp32) for the posterior first layer, one (g,s) tile each.
// grid = 64*256 blocks, 512 threads. Tile = 16 batch rows x 256 cols.
// ---------------------------------------------------------------------------
__global__ __launch_bounds__(512, 1) void k1_post_pre(
    const float* __restrict__ enc, const unsigned short* __restrict__ wq,
    const float* __restrict__ qb1, float* __restrict__ cq) {
  __shared__ unsigned short xl[16 * 264];   // stride 264 = 8*33 (16B-aligned, odd*16B)
  const int bid = blockIdx.x;
  const int g = bid >> 8, s = bid & 255;
  const int tid = threadIdx.x;
  {
    int row = tid >> 5, c0 = (tid & 31) * 8;
    const float* sp = enc + (((size_t)(g * 16 + row) * 256 + s) * 256 + c0);
    float4 a = *(const float4*)sp;
    float4 b = *(const float4*)(sp + 4);
    *(uint4*)(&xl[row * 264 + c0]) =
        make_uint4(pk2(a.x, a.y), pk2(a.z, a.w), pk2(b.x, b.y), pk2(b.z, b.w));
  }
  __syncthreads();
  const int w = tid >> 6, l = tid & 63, lm = l & 15, lg = l >> 4;
  facc4 acc0, acc1;
  { float bv = qb1[w * 32 + lm];      acc0 = (facc4){bv, bv, bv, bv}; }
  { float bv = qb1[w * 32 + 16 + lm]; acc1 = (facc4){bv, bv, bv, bv}; }
  const int nt0 = 2 * w;
#pragma unroll
  for (int kt = 0; kt < 8; ++kt) {
    bfrag8 a  = *(const bfrag8*)(&xl[lm * 264 + kt * 32 + lg * 8]);
    bfrag8 b0 = *(const bfrag8*)(wq + ((size_t)(nt0 * 8 + kt) * 64 + l) * 8);
    bfrag8 b1 = *(const bfrag8*)(wq + ((size_t)((nt0 + 1) * 8 + kt) * 64 + l) * 8);
    acc0 = mfma_bf16(a, b0, acc0);
    acc1 = mfma_bf16(a, b1, acc1);
  }
  float* dst = cq + ((size_t)bid * 512 + tid) * 8;
  *(facc4*)dst       = acc0;
  *(facc4*)(dst + 4) = acc1;
}

// ---------------------------------------------------------------------------
// K2: sequential posterior scan. grid = 64 WGs (16 batch rows each), 512 thr.
// Weights live in VGPRs as B-fragments (nt = 2w, 2w+1 per wave).
// 4 barriers/step; Cq and eps prefetched one step ahead.
// ---------------------------------------------------------------------------
__global__ __launch_bounds__(512, 1) void k2_scan(
    const float* __restrict__ prevz, const float* __restrict__ eps,
    const unsigned short* __restrict__ wU, const unsigned short* __restrict__ wW2,
    const unsigned short* __restrict__ wW3,
    const float* __restrict__ qb2, const float* __restrict__ qb3,
    const float* __restrict__ cq,
    float* __restrict__ z_o, float* __restrict__ qm_o, float* __restrict__ qlv_o) {
  __shared__ unsigned short zl[16 * 136];   // z_{s-1} bf16, stride 136 = 8*17
  __shared__ unsigned short h1[16 * 264];
  __shared__ unsigned short h2[16 * 264];
  __shared__ float el[16 * 132];            // exp(0.5*qlv), stride 132 (odd*16B)
  const int g = blockIdx.x, tid = threadIdx.x;
  const int w = tid >> 6, l = tid & 63, lm = l & 15, lg = l >> 4;
  const int rr = lg * 4;
  const int col0 = w * 32 + lm, col1 = col0 + 16;

  bfrag8 u[2][4], w2f[2][8], w3f[2][8];
#pragma unroll
  for (int j = 0; j < 2; ++j) {
    int nt = 2 * w + j;
#pragma unroll
    for (int kt = 0; kt < 4; ++kt)
      u[j][kt] = *(const bfrag8*)(wU + ((size_t)(nt * 4 + kt) * 64 + l) * 8);
#pragma unroll
    for (int kt = 0; kt < 8; ++kt)
      w2f[j][kt] = *(const bfrag8*)(wW2 + ((size_t)(nt * 8 + kt) * 64 + l) * 8);
#pragma unroll
    for (int kt = 0; kt < 8; ++kt)
      w3f[j][kt] = *(const bfrag8*)(wW3 + ((size_t)(nt * 8 + kt) * 64 + l) * 8);
  }
  const float bias2_0 = qb2[col0], bias2_1 = qb2[col1];
  const float bias3_0 = qb3[col0], bias3_1 = qb3[col1];
  {
    int row = tid >> 5, c0 = (tid & 31) * 4;
    float4 v = *(const float4*)(prevz + (size_t)(g * 16 + row) * 128 + c0);
    *(uint2*)(&zl[row * 136 + c0]) = make_uint2(pk2(v.x, v.y), pk2(v.z, v.w));
  }
  // prefetch s=0
  facc4 cb0 = *(const facc4*)(cq + ((size_t)(g * 256) * 512 + tid) * 8);
  facc4 cb1 = *(const facc4*)(cq + ((size_t)(g * 256) * 512 + tid) * 8 + 4);
  float eb0[4], eb1[4];
  if (w < 4) {
#pragma unroll
    for (int i = 0; i < 4; ++i) {
      size_t base = ((size_t)(g * 16 + rr + i) * 256) * 128;
      eb0[i] = eps[base + col0];
      eb1[i] = eps[base + col1];
    }
  }
  __syncthreads();

  for (int s = 0; s < 256; ++s) {
    facc4 a0 = cb0, a1 = cb1;
    float e0[4], e1[4];
#pragma unroll
    for (int i = 0; i < 4; ++i) { e0[i] = eb0[i]; e1[i] = eb1[i]; }
    const int sp = (s + 1 < 256) ? s + 1 : s;
    cb0 = *(const facc4*)(cq + ((size_t)(g * 256 + sp) * 512 + tid) * 8);
    cb1 = *(const facc4*)(cq + ((size_t)(g * 256 + sp) * 512 + tid) * 8 + 4);
    if (w < 4) {
#pragma unroll
      for (int i = 0; i < 4; ++i) {
        size_t base = ((size_t)(g * 16 + rr + i) * 256 + sp) * 128;
        eb0[i] = eps[base + col0];
        eb1[i] = eps[base + col1];
      }
    }
    // ---- layer 1: relu(Cq + z @ Uq) ----
#pragma unroll
    for (int kt = 0; kt < 4; ++kt) {
      bfrag8 a = *(const bfrag8*)(&zl[lm * 136 + kt * 32 + lg * 8]);
      a0 = mfma_bf16(a, u[0][kt], a0);
      a1 = mfma_bf16(a, u[1][kt], a1);
    }
#pragma unroll
    for (int i = 0; i < 4; ++i) { a0[i] = fmaxf(a0[i], 0.f); a1[i] = fmaxf(a1[i], 0.f); }
#pragma unroll
    for (int i = 0; i < 4; ++i) {
      h1[(rr + i) * 264 + col0] = f2bf(a0[i]);
      h1[(rr + i) * 264 + col1] = f2bf(a1[i]);
    }
    __syncthreads();   // A
    // ---- layer 2 ----
    facc4 b0v = (facc4){bias2_0, bias2_0, bias2_0, bias2_0};
    facc4 b1v = (facc4){bias2_1, bias2_1, bias2_1, bias2_1};
#pragma unroll
    for (int kt = 0; kt < 8; ++kt) {
      bfrag8 a = *(const bfrag8*)(&h1[lm * 264 + kt * 32 + lg * 8]);
      b0v = mfma_bf16(a, w2f[0][kt], b0v);
      b1v = mfma_bf16(a, w2f[1][kt], b1v);
    }
#pragma unroll
    for (int i = 0; i < 4; ++i) { b0v[i] = fmaxf(b0v[i], 0.f); b1v[i] = fmaxf(b1v[i], 0.f); }
#pragma unroll
    for (int i = 0; i < 4; ++i) {
      h2[(rr + i) * 264 + col0] = f2bf(b0v[i]);
      h2[(rr + i) * 264 + col1] = f2bf(b1v[i]);
    }
    __syncthreads();   // B
    // ---- layer 3 (linear) ----
    facc4 o0 = (facc4){bias3_0, bias3_0, bias3_0, bias3_0};
    facc4 o1 = (facc4){bias3_1, bias3_1, bias3_1, bias3_1};
#pragma unroll
    for (int kt = 0; kt < 8; ++kt) {
      bfrag8 a = *(const bfrag8*)(&h2[lm * 264 + kt * 32 + lg * 8]);
      o0 = mfma_bf16(a, w3f[0][kt], o0);
      o1 = mfma_bf16(a, w3f[1][kt], o1);
    }
    if (w >= 4) {   // qlv half
#pragma unroll
      for (int i = 0; i < 4; ++i) {
        size_t base = ((size_t)(g * 16 + rr + i) * 256 + s) * 128;
        qlv_o[base + col0 - 128] = o0[i];
        qlv_o[base + col1 - 128] = o1[i];
        el[(rr + i) * 132 + col0 - 128] = __expf(0.5f * o0[i]);
        el[(rr + i) * 132 + col1 - 128] = __expf(0.5f * o1[i]);
      }
    } else {        // qm half
#pragma unroll
      for (int i = 0; i < 4; ++i) {
        size_t base = ((size_t)(g * 16 + rr + i) * 256 + s) * 128;
        qm_o[base + col0] = o0[i];
        qm_o[base + col1] = o1[i];
      }
    }
    __syncthreads();   // C
    if (w < 4) {
#pragma unroll
      for (int i = 0; i < 4; ++i) {
        size_t base = ((size_t)(g * 16 + rr + i) * 256 + s) * 128;
        float z0 = o0[i] + e0[i] * el[(rr + i) * 132 + col0];
        float z1 = o1[i] + e1[i] * el[(rr + i) * 132 + col1];
        z_o[base + col0] = z0;
        z_o[base + col1] = z1;
        zl[(rr + i) * 136 + col0] = f2bf(z0);
        zl[(rr + i) * 136 + col1] = f2bf(z1);
      }
    }
    __syncthreads();   // D
  }
}

// ---------------------------------------------------------------------------
// K3: prior MLP over all (b,s), fully parallel. grid = 16384 (b, s-block of 16).
// x = [h(256) | z_prev(128)], 3 layers, outputs pm|plv (overwrites Cq region).
// ---------------------------------------------------------------------------
__global__ __launch_bounds__(512, 1) void k3_prior(
    const float* __restrict__ enc, const float* __restrict__ prevz,
    const float* __restrict__ z_in,
    const unsigned short* __restrict__ w1p, const unsigned short* __restrict__ w2p,
    const unsigned short* __restrict__ w3p,
    const float* __restrict__ pb1, const float* __restrict__ pb2,
    const float* __restrict__ pb3,
    float* __restrict__ pm_o, float* __restrict__ plv_o) {
  __shared__ unsigned short xl[16 * 392];   // 392 = 8*49 (odd*16B), cols 0..383 used
  __shared__ unsigned short h1[16 * 264];
  __shared__ unsigned short h2[16 * 264];
  const int bid = blockIdx.x;
  const int b = bid >> 4, s0 = (bid & 15) * 16;
  const int tid = threadIdx.x;
  {
    int row = tid >> 5, c0 = (tid & 31) * 8;
    const float* sp = enc + (((size_t)b * 256 + s0 + row) * 256 + c0);
    float4 a = *(const float4*)sp;
    float4 c = *(const float4*)(sp + 4);
    *(uint4*)(&xl[row * 392 + c0]) =
        make_uint4(pk2(a.x, a.y), pk2(a.z, a.w), pk2(c.x, c.y), pk2(c.z, c.w));
  }
  {
    int row = tid >> 5, c0 = (tid & 31) * 4;
    int srow = s0 + row;
    const float* sp = (srow == 0) ? (prevz + (size_t)b * 128 + c0)
                                  : (z_in + ((size_t)b * 256 + srow - 1) * 128 + c0);
    float4 v = *(const float4*)sp;
    *(uint2*)(&xl[row * 392 + 256 + c0]) = make_uint2(pk2(v.x, v.y), pk2(v.z, v.w));
  }
  __syncthreads();
  const int w = tid >> 6, l = tid & 63, lm = l & 15, lg = l >> 4;
  const int rr = lg * 4;
  const int col0 = w * 32 + lm, col1 = col0 + 16;
  const int nt0 = 2 * w;
  // ---- layer 1: K = 384 ----
  facc4 acc0, acc1;
  { float bv = pb1[col0]; acc0 = (facc4){bv, bv, bv, bv}; }
  { float bv = pb1[col1]; acc1 = (facc4){bv, bv, bv, bv}; }
#pragma unroll
  for (int kt = 0; kt < 12; ++kt) {
    bfrag8 a  = *(const bfrag8*)(&xl[lm * 392 + kt * 32 + lg * 8]);
    bfrag8 b0 = *(const bfrag8*)(w1p + ((size_t)(nt0 * 12 + kt) * 64 + l) * 8);
    bfrag8 b1 = *(const bfrag8*)(w1p + ((size_t)((nt0 + 1) * 12 + kt) * 64 + l) * 8);
    acc0 = mfma_bf16(a, b0, acc0);
    acc1 = mfma_bf16(a, b1, acc1);
  }
#pragma unroll
  for (int i = 0; i < 4; ++i) { acc0[i] = fmaxf(acc0[i], 0.f); acc1[i] = fmaxf(acc1[i], 0.f); }
#pragma unroll
  for (int i = 0; i < 4; ++i) {
    h1[(rr + i) * 264 + col0] = f2bf(acc0[i]);
    h1[(rr + i) * 264 + col1] = f2bf(acc1[i]);
  }
  __syncthreads();
  // ---- layer 2 ----
  { float bv = pb2[col0]; acc0 = (facc4){bv, bv, bv, bv}; }
  { float bv = pb2[col1]; acc1 = (facc4){bv, bv, bv, bv}; }
#pragma unroll
  for (int kt = 0; kt < 8; ++kt) {
    bfrag8 a  = *(const bfrag8*)(&h1[lm * 264 + kt * 32 + lg * 8]);
    bfrag8 b0 = *(const bfrag8*)(w2p + ((size_t)(nt0 * 8 + kt) * 64 + l) * 8);
    bfrag8 b1 = *(const bfrag8*)(w2p + ((size_t)((nt0 + 1) * 8 + kt) * 64 + l) * 8);
    acc0 = mfma_bf16(a, b0, acc0);
    acc1 = mfma_bf16(a, b1, acc1);
  }
#pragma unroll
  for (int i = 0; i < 4; ++i) { acc0[i] = fmaxf(acc0[i], 0.f); acc1[i] = fmaxf(acc1[i], 0.f); }
#pragma unroll
  for (int i = 0; i < 4; ++i) {
    h2[(rr + i) * 264 + col0] = f2bf(acc0[i]);
    h2[(rr + i) * 264 + col1] = f2bf(acc1[i]);
  }
  __syncthreads();
  // ---- layer 3 (linear) ----
  { float bv = pb3[col0]; acc0 = (facc4){bv, bv, bv, bv}; }
  { float bv = pb3[col1]; acc1 = (facc4){bv, bv, bv, bv}; }
#pragma unroll
  for (int kt = 0; kt < 8; ++kt) {
    bfrag8 a  = *(const bfrag8*)(&h2[lm * 264 + kt * 32 + lg * 8]);
    bfrag8 b0 = *(const bfrag8*)(w3p + ((size_t)(nt0 * 8 + kt) * 64 + l) * 8);
    bfrag8 b1 = *(const bfrag8*)(w3p + ((size_t)((nt0 + 1) * 8 + kt) * 64 + l) * 8);
    acc0 = mfma_bf16(a, b0, acc0);
    acc1 = mfma_bf16(a, b1, acc1);
  }
#pragma unroll
  for (int i = 0; i < 4; ++i) {
    size_t base = ((size_t)b * 256 + s0 + rr + i) * 128;
    if (w < 4) {
      pm_o[base + col0] = acc0[i];
      pm_o[base + col1] = acc1[i];
    } else {
      plv_o[base + col0 - 128] = acc0[i];
      plv_o[base + col1 - 128] = acc1[i];
    }
  }
}

// ---------------------------------------------------------------------------
extern "C" void kernel_launch(void* const* d_in, const int* in_sizes, int n_in,
                              void* d_out, int out_size, void* d_ws, size_t ws_size,
                              hipStream_t stream) {
  const float* enc   = (const float*)d_in[0];
  const float* prevz = (const float*)d_in[1];
  const float* eps   = (const float*)d_in[2];
  const float* pW1 = (const float*)d_in[3];
  const float* pb1 = (const float*)d_in[4];
  const float* pW2 = (const float*)d_in[5];
  const float* pb2 = (const float*)d_in[6];
  const float* pW3 = (const float*)d_in[7];
  const float* pb3 = (const float*)d_in[8];
  const float* qW1 = (const float*)d_in[9];
  const float* qb1 = (const float*)d_in[10];
  const float* qW2 = (const float*)d_in[11];
  const float* qb2 = (const float*)d_in[12];
  const float* qW3 = (const float*)d_in[13];
  const float* qb3 = (const float*)d_in[14];

  float* out = (float*)d_out;
  const size_t O = (size_t)1024 * 256 * 128;
  float* z_o   = out;
  float* pm_o  = out + O;
  float* plv_o = out + 2 * O;
  float* qm_o  = out + 3 * O;
  float* qlv_o = out + 4 * O;
  float* cq = pm_o;   // Cq (2*O floats) borrows pm|plv region; K3 overwrites it later

  unsigned short* ws = (unsigned short*)d_ws;
  unsigned short* Wqe = ws;             // 65536 elems
  unsigned short* Uq  = ws + 65536;     // 32768
  unsigned short* W2q = ws + 98304;     // 65536
  unsigned short* W3q = ws + 163840;    // 65536
  unsigned short* W1p = ws + 229376;    // 98304
  unsigned short* W2p = ws + 327680;    // 65536
  unsigned short* W3p = ws + 393216;    // 65536  (total 458752 elems = 896 KB)

  pack_weights<<<32, 256, 0, stream>>>(qW1, qW1 + 384 * 256, Wqe, 8);   // h-part sum
  pack_weights<<<16, 256, 0, stream>>>(qW1 + 256 * 256, nullptr, Uq, 4);
  pack_weights<<<32, 256, 0, stream>>>(qW2, nullptr, W2q, 8);
  pack_weights<<<32, 256, 0, stream>>>(qW3, nullptr, W3q, 8);
  pack_weights<<<48, 256, 0, stream>>>(pW1, nullptr, W1p, 12);
  pack_weights<<<32, 256, 0, stream>>>(pW2, nullptr, W2p, 8);
  pack_weights<<<32, 256, 0, stream>>>(pW3, nullptr, W3p, 8);

  k1_post_pre<<<16384, 512, 0, stream>>>(enc, Wqe, qb1, cq);
  k2_scan<<<64, 512, 0, stream>>>(prevz, eps, Uq, W2q, W3q, qb2, qb3, cq,
                                  z_o, qm_o, qlv_o);
  k3_prior<<<16384, 512, 0, stream>>>(enc, prevz, z_o, W1p, W2p, W3p,
                                      pb1, pb2, pb3, pm_o, plv_o);
}

// Round 2
// 689.941 us; speedup vs baseline: 2.1764x; 2.1764x over previous
//
#include <hip/hip_runtime.h>

// ---------------------------------------------------------------------------
// ConditionalVariationalModule: B=1024, S=256, INPUT=256, LATENT=128, HIDDEN=256
//   K1: Cq = h@(qW1[0:256]+qW1[384:640]) + qb1  (parallel, bf16 frag-packed out)
//   K2: sequential posterior scan, 64 WGs x 16 rows, weights in VGPRs,
//       raw barriers (no vmcnt drain), 3 barriers/step, in-wave z.
//   K3: prior MLP over all (b,s), M=32 row-tiles (overwrites Cq region).
// Outputs (fp32): z | pm | plv | qm | qlv, each [B,S,128]. Cq lives in pm.
// ---------------------------------------------------------------------------

typedef __attribute__((ext_vector_type(8))) short bfrag8;   // 8 bf16 = 4 VGPR
typedef __attribute__((ext_vector_type(4))) float facc4;    // MFMA accum

__device__ __forceinline__ unsigned short f2bf(float x) {
  unsigned int u = __float_as_uint(x);
  u = (u + 0x7fffu + ((u >> 16) & 1u)) >> 16;   // RNE
  return (unsigned short)u;
}
__device__ __forceinline__ unsigned int pk2(float a, float b) {
  return (unsigned int)f2bf(a) | ((unsigned int)f2bf(b) << 16);
}
__device__ __forceinline__ float bf2f(unsigned int lo16) {
  return __uint_as_float(lo16 << 16);
}
__device__ __forceinline__ facc4 mfma_bf16(bfrag8 a, bfrag8 b, facc4 c) {
  return __builtin_amdgcn_mfma_f32_16x16x32_bf16(a, b, c, 0, 0, 0);
}
// raw workgroup barrier: LDS ordering only, NO vmcnt(0) drain
__device__ __forceinline__ void wg_barrier() {
  asm volatile("s_waitcnt lgkmcnt(0)" ::: "memory");
  __builtin_amdgcn_sched_barrier(0);
  __builtin_amdgcn_s_barrier();
  __builtin_amdgcn_sched_barrier(0);
}
// bank-conflict swizzle for bf16 LDS tiles (apply on BOTH write and read)
#define SWC(r, c) ((c) ^ (((r) & 8) << 1))

// ---------------------------------------------------------------------------
// One kernel packs all 7 weight matrices into B-fragment order.
// dst[((nt*KT+kt)*64+l)*8+i] = bf16( W[kt*32+(l>>4)*8+i][nt*16+(l&15)] )
// ---------------------------------------------------------------------------
__global__ void pack_all(const float* __restrict__ qW1, const float* __restrict__ qW2,
                         const float* __restrict__ qW3, const float* __restrict__ pW1,
                         const float* __restrict__ pW2, const float* __restrict__ pW3,
                         unsigned short* __restrict__ ws) {
  int b = blockIdx.x;
  const float* src; const float* src2 = nullptr; unsigned short* dst; int KT;
  if (b < 32)       { src = qW1; src2 = qW1 + 384 * 256; dst = ws;          KT = 8; }
  else if (b < 48)  { b -= 32;  src = qW1 + 256 * 256;   dst = ws + 65536;  KT = 4; }
  else if (b < 80)  { b -= 48;  src = qW2;               dst = ws + 98304;  KT = 8; }
  else if (b < 112) { b -= 80;  src = qW3;               dst = ws + 163840; KT = 8; }
  else if (b < 160) { b -= 112; src = pW1;               dst = ws + 229376; KT = 12; }
  else if (b < 192) { b -= 160; src = pW2;               dst = ws + 327680; KT = 8; }
  else              { b -= 192; src = pW3;               dst = ws + 393216; KT = 8; }
  int t = b * 256 + (int)threadIdx.x;
  if (t >= 16 * KT * 64) return;
  int l  = t & 63;
  int kt = (t >> 6) % KT;
  int nt = t / (64 * KT);
  int n  = nt * 16 + (l & 15);
  int k0 = kt * 32 + (l >> 4) * 8;
  unsigned int o[4];
#pragma unroll
  for (int p = 0; p < 4; ++p) {
    float a = src[(size_t)(k0 + 2 * p) * 256 + n];
    float c = src[(size_t)(k0 + 2 * p + 1) * 256 + n];
    if (src2) {
      a += src2[(size_t)(k0 + 2 * p) * 256 + n];
      c += src2[(size_t)(k0 + 2 * p + 1) * 256 + n];
    }
    o[p] = pk2(a, c);
  }
  *(uint4*)(dst + (size_t)t * 8) = make_uint4(o[0], o[1], o[2], o[3]);
}

// ---------------------------------------------------------------------------
// K1: Cq bf16 frag-packed. grid = 8192 (gp=32-row pair group, s). 512 thr.
// ---------------------------------------------------------------------------
__global__ __launch_bounds__(512, 4) void k1_post_pre(
    const float* __restrict__ enc, const unsigned short* __restrict__ wq,
    const float* __restrict__ qb1, unsigned short* __restrict__ cq) {
  __shared__ unsigned short xl[32 * 264];
  const int bid = blockIdx.x;
  const int gp = bid >> 8, s = bid & 255;
  const int tid = threadIdx.x;
  {
    int row = tid >> 4, c0 = (tid & 15) * 16;
    const float* sp = enc + (((size_t)(gp * 32 + row) * 256 + s) * 256 + c0);
    float4 a = *(const float4*)sp;
    float4 b = *(const float4*)(sp + 4);
    float4 c = *(const float4*)(sp + 8);
    float4 d = *(const float4*)(sp + 12);
    int cc = SWC(row, c0);
    *(uint4*)(&xl[row * 264 + cc]) =
        make_uint4(pk2(a.x, a.y), pk2(a.z, a.w), pk2(b.x, b.y), pk2(b.z, b.w));
    *(uint4*)(&xl[row * 264 + cc + 8]) =
        make_uint4(pk2(c.x, c.y), pk2(c.z, c.w), pk2(d.x, d.y), pk2(d.z, d.w));
  }
  __syncthreads();
  const int w = tid >> 6, l = tid & 63, lm = l & 15, lg = l >> 4;
  facc4 a00, a01, a10, a11;
  { float bv = qb1[w * 16 + lm];       a00 = (facc4){bv, bv, bv, bv}; a10 = a00; }
  { float bv = qb1[128 + w * 16 + lm]; a01 = (facc4){bv, bv, bv, bv}; a11 = a01; }
#pragma unroll
  for (int kt = 0; kt < 8; ++kt) {
    bfrag8 b0 = *(const bfrag8*)(wq + ((size_t)(w * 8 + kt) * 64 + l) * 8);
    bfrag8 b1 = *(const bfrag8*)(wq + ((size_t)((w + 8) * 8 + kt) * 64 + l) * 8);
    int kk = SWC(lm, kt * 32 + lg * 8);
    bfrag8 x0 = *(const bfrag8*)(&xl[lm * 264 + kk]);
    bfrag8 x1 = *(const bfrag8*)(&xl[(16 + lm) * 264 + kk]);
    a00 = mfma_bf16(x0, b0, a00); a01 = mfma_bf16(x0, b1, a01);
    a10 = mfma_bf16(x1, b0, a10); a11 = mfma_bf16(x1, b1, a11);
  }
  size_t o0 = ((size_t)((gp * 2 + 0) * 256 + s) * 512 + tid) * 8;
  size_t o1 = ((size_t)((gp * 2 + 1) * 256 + s) * 512 + tid) * 8;
  *(uint4*)(cq + o0) = make_uint4(pk2(a00[0], a00[1]), pk2(a00[2], a00[3]),
                                  pk2(a01[0], a01[1]), pk2(a01[2], a01[3]));
  *(uint4*)(cq + o1) = make_uint4(pk2(a10[0], a10[1]), pk2(a10[2], a10[3]),
                                  pk2(a11[0], a11[1]), pk2(a11[2], a11[3]));
}

// ---------------------------------------------------------------------------
// K2: sequential posterior scan. 64 WGs x 512 thr. Weights VGPR-resident
// (non-restrict pointers forbid rematerialization past in-loop stores).
// Wave w owns cols [16w,16w+16) and [128+16w, ...): z computed in-wave.
// ---------------------------------------------------------------------------
__global__ __launch_bounds__(512, 1) void k2_scan(
    const float* __restrict__ prevz, const float* __restrict__ eps,
    const unsigned short* wU, const unsigned short* wW2, const unsigned short* wW3,
    const float* __restrict__ qb2, const float* __restrict__ qb3,
    const unsigned short* __restrict__ cq,
    float* z_o, float* qm_o, float* qlv_o) {
  __shared__ unsigned short zl[16 * 136];
  __shared__ unsigned short h1[16 * 264];
  __shared__ unsigned short h2[16 * 264];
  const int g = blockIdx.x, tid = threadIdx.x;
  const int w = tid >> 6, l = tid & 63, lm = l & 15, lg = l >> 4;
  const int rr = lg * 4;
  const int col = w * 16 + lm;

  bfrag8 u0[4], u1[4], w2a[8], w2b[8], w3a[8], w3b[8];
#pragma unroll
  for (int kt = 0; kt < 4; ++kt) {
    u0[kt] = *(const bfrag8*)(wU + ((size_t)(w * 4 + kt) * 64 + l) * 8);
    u1[kt] = *(const bfrag8*)(wU + ((size_t)((w + 8) * 4 + kt) * 64 + l) * 8);
  }
#pragma unroll
  for (int kt = 0; kt < 8; ++kt) {
    w2a[kt] = *(const bfrag8*)(wW2 + ((size_t)(w * 8 + kt) * 64 + l) * 8);
    w2b[kt] = *(const bfrag8*)(wW2 + ((size_t)((w + 8) * 8 + kt) * 64 + l) * 8);
    w3a[kt] = *(const bfrag8*)(wW3 + ((size_t)(w * 8 + kt) * 64 + l) * 8);
    w3b[kt] = *(const bfrag8*)(wW3 + ((size_t)((w + 8) * 8 + kt) * 64 + l) * 8);
  }
  const float b2a = qb2[col], b2b = qb2[128 + col];
  const float b3a = qb3[col], b3b = qb3[128 + col];
  {
    int row = tid >> 5, c0 = (tid & 31) * 4;
    float4 v = *(const float4*)(prevz + (size_t)(g * 16 + row) * 128 + c0);
    *(uint2*)(&zl[row * 136 + SWC(row, c0)]) = make_uint2(pk2(v.x, v.y), pk2(v.z, v.w));
  }
  const size_t r0 = ((size_t)(g * 16 + rr) * 256) * 128 + col;   // (row rr, s=0)
  const uint4* cqv = (const uint4*)cq + (size_t)(g * 256) * 512 + tid;
  uint4 cb = cqv[0];
  float eb[4];
#pragma unroll
  for (int i = 0; i < 4; ++i) eb[i] = eps[r0 + (size_t)i * 32768];
  __syncthreads();

  for (int s = 0; s < 256; ++s) {
    const int sn = (s + 1 < 256) ? s + 1 : s;
    uint4 cbn = cqv[(size_t)sn * 512];
    float ebn[4];
#pragma unroll
    for (int i = 0; i < 4; ++i)
      ebn[i] = eps[r0 + (size_t)i * 32768 + (size_t)sn * 128];
    // ---- layer 1: relu(Cq + z @ Uq) ----
    facc4 a0, a1;
    a0[0] = bf2f(cb.x & 0xffffu); a0[1] = bf2f(cb.x >> 16);
    a0[2] = bf2f(cb.y & 0xffffu); a0[3] = bf2f(cb.y >> 16);
    a1[0] = bf2f(cb.z & 0xffffu); a1[1] = bf2f(cb.z >> 16);
    a1[2] = bf2f(cb.w & 0xffffu); a1[3] = bf2f(cb.w >> 16);
#pragma unroll
    for (int kt = 0; kt < 4; ++kt) {
      bfrag8 a = *(const bfrag8*)(&zl[lm * 136 + SWC(lm, kt * 32 + lg * 8)]);
      a0 = mfma_bf16(a, u0[kt], a0);
      a1 = mfma_bf16(a, u1[kt], a1);
    }
#pragma unroll
    for (int i = 0; i < 4; ++i) {
      h1[(rr + i) * 264 + SWC(rr + i, col)]       = f2bf(fmaxf(a0[i], 0.f));
      h1[(rr + i) * 264 + SWC(rr + i, 128 + col)] = f2bf(fmaxf(a1[i], 0.f));
    }
    wg_barrier();
    // ---- layer 2 ----
    facc4 c0v = (facc4){b2a, b2a, b2a, b2a};
    facc4 c1v = (facc4){b2b, b2b, b2b, b2b};
#pragma unroll
    for (int kt = 0; kt < 8; ++kt) {
      bfrag8 a = *(const bfrag8*)(&h1[lm * 264 + SWC(lm, kt * 32 + lg * 8)]);
      c0v = mfma_bf16(a, w2a[kt], c0v);
      c1v = mfma_bf16(a, w2b[kt], c1v);
    }
#pragma unroll
    for (int i = 0; i < 4; ++i) {
      h2[(rr + i) * 264 + SWC(rr + i, col)]       = f2bf(fmaxf(c0v[i], 0.f));
      h2[(rr + i) * 264 + SWC(rr + i, 128 + col)] = f2bf(fmaxf(c1v[i], 0.f));
    }
    wg_barrier();
    // ---- layer 3 (linear) + reparameterization, all in-wave ----
    facc4 o0 = (facc4){b3a, b3a, b3a, b3a};
    facc4 o1 = (facc4){b3b, b3b, b3b, b3b};
#pragma unroll
    for (int kt = 0; kt < 8; ++kt) {
      bfrag8 a = *(const bfrag8*)(&h2[lm * 264 + SWC(lm, kt * 32 + lg * 8)]);
      o0 = mfma_bf16(a, w3a[kt], o0);
      o1 = mfma_bf16(a, w3b[kt], o1);
    }
    const size_t sb = r0 + (size_t)s * 128;
#pragma unroll
    for (int i = 0; i < 4; ++i) {
      float zq = o0[i] + eb[i] * __expf(0.5f * o1[i]);
      size_t ix = sb + (size_t)i * 32768;
      qm_o[ix]  = o0[i];
      qlv_o[ix] = o1[i];
      z_o[ix]   = zq;
      zl[(rr + i) * 136 + SWC(rr + i, col)] = f2bf(zq);
    }
    wg_barrier();
    cb = cbn;
#pragma unroll
    for (int i = 0; i < 4; ++i) eb[i] = ebn[i];
  }
}

// ---------------------------------------------------------------------------
// K3: prior MLP, M=32 row-tiles. grid = 8192 (b, 32-step chunk). h2 reuses xl.
// ---------------------------------------------------------------------------
__global__ __launch_bounds__(512, 4) void k3_prior(
    const float* __restrict__ enc, const float* __restrict__ prevz,
    const float* __restrict__ z_in,
    const unsigned short* __restrict__ w1p, const unsigned short* __restrict__ w2p,
    const unsigned short* __restrict__ w3p,
    const float* __restrict__ pb1, const float* __restrict__ pb2,
    const float* __restrict__ pb3,
    float* __restrict__ pm_o, float* __restrict__ plv_o) {
  __shared__ unsigned short xl[32 * 392];   // x (384 cols); reused as h2 (256 cols)
  __shared__ unsigned short h1[32 * 264];
  const int bid = blockIdx.x;
  const int b = bid >> 3, s0 = (bid & 7) * 32;
  const int tid = threadIdx.x;
  {
    int row = tid >> 4, c0 = (tid & 15) * 16;
    const float* sp = enc + (((size_t)b * 256 + s0 + row) * 256 + c0);
    float4 a = *(const float4*)sp;
    float4 c = *(const float4*)(sp + 4);
    float4 d = *(const float4*)(sp + 8);
    float4 e = *(const float4*)(sp + 12);
    int cc = SWC(row, c0);
    *(uint4*)(&xl[row * 392 + cc]) =
        make_uint4(pk2(a.x, a.y), pk2(a.z, a.w), pk2(c.x, c.y), pk2(c.z, c.w));
    *(uint4*)(&xl[row * 392 + cc + 8]) =
        make_uint4(pk2(d.x, d.y), pk2(d.z, d.w), pk2(e.x, e.y), pk2(e.z, e.w));
  }
  {
    int row = tid >> 4, c0 = (tid & 15) * 8;
    int srow = s0 + row;
    const float* sp = (srow == 0) ? (prevz + (size_t)b * 128 + c0)
                                  : (z_in + ((size_t)b * 256 + srow - 1) * 128 + c0);
    float4 v0 = *(const float4*)sp;
    float4 v1 = *(const float4*)(sp + 4);
    int cc = SWC(row, 256 + c0);
    *(uint4*)(&xl[row * 392 + cc]) =
        make_uint4(pk2(v0.x, v0.y), pk2(v0.z, v0.w), pk2(v1.x, v1.y), pk2(v1.z, v1.w));
  }
  __syncthreads();
  const int w = tid >> 6, l = tid & 63, lm = l & 15, lg = l >> 4;
  const int rr = lg * 4;
  const int col = w * 16 + lm;
  facc4 a00, a01, a10, a11;
  // ---- layer 1: K = 384 ----
  { float bv = pb1[col];       a00 = (facc4){bv, bv, bv, bv}; a10 = a00; }
  { float bv = pb1[128 + col]; a01 = (facc4){bv, bv, bv, bv}; a11 = a01; }
#pragma unroll
  for (int kt = 0; kt < 12; ++kt) {
    bfrag8 b0 = *(const bfrag8*)(w1p + ((size_t)(w * 12 + kt) * 64 + l) * 8);
    bfrag8 b1 = *(const bfrag8*)(w1p + ((size_t)((w + 8) * 12 + kt) * 64 + l) * 8);
    int kk = SWC(lm, kt * 32 + lg * 8);
    bfrag8 x0 = *(const bfrag8*)(&xl[lm * 392 + kk]);
    bfrag8 x1 = *(const bfrag8*)(&xl[(16 + lm) * 392 + kk]);
    a00 = mfma_bf16(x0, b0, a00); a01 = mfma_bf16(x0, b1, a01);
    a10 = mfma_bf16(x1, b0, a10); a11 = mfma_bf16(x1, b1, a11);
  }
#pragma unroll
  for (int i = 0; i < 4; ++i) {
    h1[(rr + i) * 264 + SWC(rr + i, col)]              = f2bf(fmaxf(a00[i], 0.f));
    h1[(rr + i) * 264 + SWC(rr + i, 128 + col)]        = f2bf(fmaxf(a01[i], 0.f));
    h1[(16 + rr + i) * 264 + SWC(rr + i, col)]         = f2bf(fmaxf(a10[i], 0.f));
    h1[(16 + rr + i) * 264 + SWC(rr + i, 128 + col)]   = f2bf(fmaxf(a11[i], 0.f));
  }
  __syncthreads();
  // ---- layer 2 (reads h1, writes into xl region) ----
  { float bv = pb2[col];       a00 = (facc4){bv, bv, bv, bv}; a10 = a00; }
  { float bv = pb2[128 + col]; a01 = (facc4){bv, bv, bv, bv}; a11 = a01; }
#pragma unroll
  for (int kt = 0; kt < 8; ++kt) {
    bfrag8 b0 = *(const bfrag8*)(w2p + ((size_t)(w * 8 + kt) * 64 + l) * 8);
    bfrag8 b1 = *(const bfrag8*)(w2p + ((size_t)((w + 8) * 8 + kt) * 64 + l) * 8);
    int kk = SWC(lm, kt * 32 + lg * 8);
    bfrag8 x0 = *(const bfrag8*)(&h1[lm * 264 + kk]);
    bfrag8 x1 = *(const bfrag8*)(&h1[(16 + lm) * 264 + kk]);
    a00 = mfma_bf16(x0, b0, a00); a01 = mfma_bf16(x0, b1, a01);
    a10 = mfma_bf16(x1, b0, a10); a11 = mfma_bf16(x1, b1, a11);
  }
  __syncthreads();   // all h1 reads done before overwriting xl? (xl != h1; safe) -- also xl reads done in L1
#pragma unroll
  for (int i = 0; i < 4; ++i) {
    xl[(rr + i) * 392 + SWC(rr + i, col)]              = f2bf(fmaxf(a00[i], 0.f));
    xl[(rr + i) * 392 + SWC(rr + i, 128 + col)]        = f2bf(fmaxf(a01[i], 0.f));
    xl[(16 + rr + i) * 392 + SWC(rr + i, col)]         = f2bf(fmaxf(a10[i], 0.f));
    xl[(16 + rr + i) * 392 + SWC(rr + i, 128 + col)]   = f2bf(fmaxf(a11[i], 0.f));
  }
  __syncthreads();
  // ---- layer 3 (linear, reads xl-as-h2) ----
  { float bv = pb3[col];       a00 = (facc4){bv, bv, bv, bv}; a10 = a00; }
  { float bv = pb3[128 + col]; a01 = (facc4){bv, bv, bv, bv}; a11 = a01; }
#pragma unroll
  for (int kt = 0; kt < 8; ++kt) {
    bfrag8 b0 = *(const bfrag8*)(w3p + ((size_t)(w * 8 + kt) * 64 + l) * 8);
    bfrag8 b1 = *(const bfrag8*)(w3p + ((size_t)((w + 8) * 8 + kt) * 64 + l) * 8);
    int kk = SWC(lm, kt * 32 + lg * 8);
    bfrag8 x0 = *(const bfrag8*)(&xl[lm * 392 + kk]);
    bfrag8 x1 = *(const bfrag8*)(&xl[(16 + lm) * 392 + kk]);
    a00 = mfma_bf16(x0, b0, a00); a01 = mfma_bf16(x0, b1, a01);
    a10 = mfma_bf16(x1, b0, a10); a11 = mfma_bf16(x1, b1, a11);
  }
#pragma unroll
  for (int i = 0; i < 4; ++i) {
    size_t base0 = ((size_t)b * 256 + s0 + rr + i) * 128;
    size_t base1 = ((size_t)b * 256 + s0 + 16 + rr + i) * 128;
    pm_o[base0 + col]  = a00[i];
    plv_o[base0 + col] = a01[i];
    pm_o[base1 + col]  = a10[i];
    plv_o[base1 + col] = a11[i];
  }
}

// ---------------------------------------------------------------------------
extern "C" void kernel_launch(void* const* d_in, const int* in_sizes, int n_in,
                              void* d_out, int out_size, void* d_ws, size_t ws_size,
                              hipStream_t stream) {
  const float* enc   = (const float*)d_in[0];
  const float* prevz = (const float*)d_in[1];
  const float* eps   = (const float*)d_in[2];
  const float* pW1 = (const float*)d_in[3];
  const float* pb1 = (const float*)d_in[4];
  const float* pW2 = (const float*)d_in[5];
  const float* pb2 = (const float*)d_in[6];
  const float* pW3 = (const float*)d_in[7];
  const float* pb3 = (const float*)d_in[8];
  const float* qW1 = (const float*)d_in[9];
  const float* qb1 = (const float*)d_in[10];
  const float* qW2 = (const float*)d_in[11];
  const float* qb2 = (const float*)d_in[12];
  const float* qW3 = (const float*)d_in[13];
  const float* qb3 = (const float*)d_in[14];

  float* out = (float*)d_out;
  const size_t O = (size_t)1024 * 256 * 128;
  float* z_o   = out;
  float* pm_o  = out + O;
  float* plv_o = out + 2 * O;
  float* qm_o  = out + 3 * O;
  float* qlv_o = out + 4 * O;
  unsigned short* cq = (unsigned short*)pm_o;  // bf16 Cq (2*O shorts = O floats)

  unsigned short* ws = (unsigned short*)d_ws;
  unsigned short* Wqe = ws;             // 65536 elems
  unsigned short* Uq  = ws + 65536;     // 32768
  unsigned short* W2q = ws + 98304;     // 65536
  unsigned short* W3q = ws + 163840;    // 65536
  unsigned short* W1p = ws + 229376;    // 98304
  unsigned short* W2p = ws + 327680;    // 65536
  unsigned short* W3p = ws + 393216;    // 65536

  pack_all<<<224, 256, 0, stream>>>(qW1, qW2, qW3, pW1, pW2, pW3, ws);
  k1_post_pre<<<8192, 512, 0, stream>>>(enc, Wqe, qb1, cq);
  k2_scan<<<64, 512, 0, stream>>>(prevz, eps, Uq, W2q, W3q, qb2, qb3, cq,
                                  z_o, qm_o, qlv_o);
  k3_prior<<<8192, 512, 0, stream>>>(enc, prevz, z_o, W1p, W2p, W3p,
                                     pb1, pb2, pb3, pm_o, plv_o);
}